// Round 1
// baseline (2821.562 us; speedup 1.0000x reference)
//
#include <hip/hip_runtime.h>
#include <math.h>

#define NNODES 100000
#define NEDGES 1600000
#define NREL   4
#define DIN    38
#define HID    64
#define NGRAPH 1000
#define TN     16   // nodes per transform block

__device__ __forceinline__ float wsum64(float v) {
    #pragma unroll
    for (int o = 32; o; o >>= 1) v += __shfl_xor(v, o);
    return v;
}

// ---------------------------------------------------------------------------
// counts: cnt[node*R+rel] edge counts, gcnt[g] nodes per graph
// ---------------------------------------------------------------------------
__global__ __launch_bounds__(256) void count_kernel(
    const int* __restrict__ ei, const int* __restrict__ et,
    const int* __restrict__ batch, int* __restrict__ cnt,
    int* __restrict__ gcnt) {
    int i = blockIdx.x * 256 + threadIdx.x;
    if (i < NEDGES) {
        int dst = ei[NEDGES + i];
        atomicAdd(&cnt[dst * NREL + et[i]], 1);
    }
    if (i < NNODES) {
        atomicAdd(&gcnt[batch[i]], 1);
    }
}

// ---------------------------------------------------------------------------
// scatter: one wave handles 64 edges; lane = feature channel.
// sums[(dst*R+etype)*F + f] += x[src*F + f]
// ---------------------------------------------------------------------------
template <int F>
__global__ __launch_bounds__(256) void scatter_kernel(
    const float* __restrict__ x, const int* __restrict__ ei,
    const int* __restrict__ et, float* __restrict__ sums) {
    int gtid = blockIdx.x * 256 + threadIdx.x;
    int wid = gtid >> 6;
    int lane = threadIdx.x & 63;
    int ebase = wid << 6;
    if (ebase >= NEDGES) return;
    int e = ebase + lane;
    int src = 0, seg = 0;
    if (e < NEDGES) {
        src = ei[e];
        int dst = ei[NEDGES + e];
        seg = dst * NREL + et[e];
    }
    int nE = NEDGES - ebase; if (nE > 64) nE = 64;
    for (int j = 0; j < nE; ++j) {
        int sj = __shfl(src, j);
        int gj = __shfl(seg, j);
        if (lane < F) {
            atomicAdd(sums + (size_t)gj * F + lane, x[(size_t)sj * F + lane]);
        }
    }
}

// ---------------------------------------------------------------------------
// transform layer 0: K = 152 (W0 over mean) + 38 (root0 over x) + 38 (res_w
// over x) = 228 virtual rows. accA = conv part, accB = residual projection.
// x1 = LN(relu(accA + b0) + accB + res_b)
// ---------------------------------------------------------------------------
__global__ __launch_bounds__(256) void transform0_kernel(
    const float* __restrict__ x, const float* __restrict__ sums,
    const int* __restrict__ cnt, const float* __restrict__ W0,
    const float* __restrict__ root0, const float* __restrict__ b0,
    const float* __restrict__ lng, const float* __restrict__ lnb,
    const float* __restrict__ resw, const float* __restrict__ resb,
    float* __restrict__ x1) {
    const int K0 = NREL * DIN;   // 152
    const int K1 = K0 + DIN;     // 190
    const int K  = K1 + DIN;     // 228
    __shared__ float wl[64][64];
    __shared__ float nv[TN][228];
    int tid = threadIdx.x;
    int nbase = blockIdx.x * TN;

    // stage node vectors [mean(152) | x(38) | x(38)]
    for (int idx = tid; idx < TN * K; idx += 256) {
        int nl = idx / K, t = idx - nl * K;
        int n = nbase + nl;
        float v = 0.f;
        if (n < NNODES) {
            if (t < K0) {
                int r = t / DIN, f = t - r * DIN;
                int c = cnt[n * NREL + r];
                float cc = c > 0 ? (float)c : 1.0f;
                v = sums[((size_t)n * NREL + r) * DIN + f] / cc;
            } else if (t < K1) {
                v = x[(size_t)n * DIN + (t - K0)];
            } else {
                v = x[(size_t)n * DIN + (t - K1)];
            }
        }
        nv[nl][t] = v;
    }

    int wv = tid >> 6, lane = tid & 63;
    float accA[4] = {0.f, 0.f, 0.f, 0.f};
    float accB[4] = {0.f, 0.f, 0.f, 0.f};

    for (int kc = 0; kc < 4; ++kc) {
        int kbeg = kc * 64;
        int kn = K - kbeg; if (kn > 64) kn = 64;
        // stage weight rows (virtual concat W0 | root0 | res_w)
        for (int idx = tid; idx < kn * 64; idx += 256) {
            int row = idx >> 6, col = idx & 63;
            int grow = kbeg + row;
            float w;
            if (grow < K0)      w = W0[grow * 64 + col];
            else if (grow < K1) w = root0[(grow - K0) * 64 + col];
            else                w = resw[(grow - K1) * 64 + col];
            wl[row][col] = w;
        }
        __syncthreads();
        int n0 = wv * 4;
        for (int k = 0; k < kn; ++k) {
            float wval = wl[k][lane];
            int gk = kbeg + k;
            if (gk < K1) {
                accA[0] += nv[n0 + 0][gk] * wval;
                accA[1] += nv[n0 + 1][gk] * wval;
                accA[2] += nv[n0 + 2][gk] * wval;
                accA[3] += nv[n0 + 3][gk] * wval;
            } else {
                accB[0] += nv[n0 + 0][gk] * wval;
                accB[1] += nv[n0 + 1][gk] * wval;
                accB[2] += nv[n0 + 2][gk] * wval;
                accB[3] += nv[n0 + 3][gk] * wval;
            }
        }
        __syncthreads();
    }

    for (int j = 0; j < 4; ++j) {
        int n = nbase + wv * 4 + j;
        if (n >= NNODES) break;
        float h = fmaxf(accA[j] + b0[lane], 0.f);
        float u = h + accB[j] + resb[lane];
        float mu = wsum64(u) * (1.f / 64.f);
        float d = u - mu;
        float var = wsum64(d * d) * (1.f / 64.f);
        float xn = d * (1.f / sqrtf(var + 1e-5f)) * lng[lane] + lnb[lane];
        x1[(size_t)n * HID + lane] = xn;
    }
}

// ---------------------------------------------------------------------------
// transform layers 1/2: K = 256 (W over mean) + 64 (root over xprev) = 320.
// out = LN(relu(acc + b) + xprev). POOL: atomically accumulate into pooled.
// ---------------------------------------------------------------------------
template <bool POOL>
__global__ __launch_bounds__(256) void transform12_kernel(
    const float* __restrict__ xprev, const float* __restrict__ sums,
    const int* __restrict__ cnt, const float* __restrict__ W,
    const float* __restrict__ root, const float* __restrict__ bias,
    const float* __restrict__ lng, const float* __restrict__ lnb,
    const int* __restrict__ batch, float* __restrict__ dst) {
    __shared__ float wl[64][64];
    __shared__ float nv[TN][320];
    int tid = threadIdx.x;
    int nbase = blockIdx.x * TN;

    for (int idx = tid; idx < TN * 320; idx += 256) {
        int nl = idx / 320, t = idx - nl * 320;
        int n = nbase + nl;
        float v = 0.f;
        if (n < NNODES) {
            if (t < 256) {
                int r = t >> 6;
                int c = cnt[n * NREL + r];
                float cc = c > 0 ? (float)c : 1.0f;
                v = sums[((size_t)n * NREL + r) * HID + (t & 63)] / cc;
            } else {
                v = xprev[(size_t)n * HID + (t - 256)];
            }
        }
        nv[nl][t] = v;
    }

    int wv = tid >> 6, lane = tid & 63;
    float acc[4] = {0.f, 0.f, 0.f, 0.f};

    for (int kc = 0; kc < 5; ++kc) {
        int kbeg = kc * 64;
        for (int idx = tid; idx < 64 * 64; idx += 256) {
            int row = idx >> 6, col = idx & 63;
            int grow = kbeg + row;
            wl[row][col] = (grow < 256) ? W[grow * 64 + col]
                                        : root[(grow - 256) * 64 + col];
        }
        __syncthreads();
        int n0 = wv * 4;
        #pragma unroll 8
        for (int k = 0; k < 64; ++k) {
            float wval = wl[k][lane];
            acc[0] += nv[n0 + 0][kbeg + k] * wval;
            acc[1] += nv[n0 + 1][kbeg + k] * wval;
            acc[2] += nv[n0 + 2][kbeg + k] * wval;
            acc[3] += nv[n0 + 3][kbeg + k] * wval;
        }
        __syncthreads();
    }

    for (int j = 0; j < 4; ++j) {
        int nl = wv * 4 + j;
        int n = nbase + nl;
        if (n >= NNODES) break;
        float h = fmaxf(acc[j] + bias[lane], 0.f);
        float u = h + nv[nl][256 + lane];
        float mu = wsum64(u) * (1.f / 64.f);
        float d = u - mu;
        float var = wsum64(d * d) * (1.f / 64.f);
        float xn = d * (1.f / sqrtf(var + 1e-5f)) * lng[lane] + lnb[lane];
        if (POOL) {
            int g = batch[n];
            atomicAdd(dst + (size_t)g * HID + lane, xn);
        } else {
            dst[(size_t)n * HID + lane] = xn;
        }
    }
}

// ---------------------------------------------------------------------------
// readout: out[g] = relu(pooled[g]/cnt @ ro_w1 + ro_b1) @ ro_w2 + ro_b2
// one wave per graph, lane = hidden channel
// ---------------------------------------------------------------------------
__global__ __launch_bounds__(256) void readout_kernel(
    const float* __restrict__ pooled, const int* __restrict__ gcnt,
    const float* __restrict__ w1, const float* __restrict__ b1,
    const float* __restrict__ w2, const float* __restrict__ b2,
    float* __restrict__ out) {
    __shared__ float wl[64][64];
    int tid = threadIdx.x;
    for (int idx = tid; idx < 64 * 64; idx += 256) {
        wl[idx >> 6][idx & 63] = w1[idx];
    }
    __syncthreads();
    int wv = tid >> 6, lane = tid & 63;
    int g = blockIdx.x * 4 + wv;
    if (g >= NGRAPH) return;
    int c = gcnt[g];
    float cc = c > 0 ? (float)c : 1.0f;
    float p = pooled[(size_t)g * HID + lane] / cc;
    float acc = b1[lane];
    for (int f = 0; f < 64; ++f) {
        acc += __shfl(p, f) * wl[f][lane];
    }
    float t = fmaxf(acc, 0.f);
    float v = t * w2[lane];
    v = wsum64(v);
    if (lane == 0) out[g] = v + b2[0];
}

// ---------------------------------------------------------------------------
extern "C" void kernel_launch(void* const* d_in, const int* in_sizes, int n_in,
                              void* d_out, int out_size, void* d_ws, size_t ws_size,
                              hipStream_t stream) {
    const float* x     = (const float*)d_in[0];
    const int*   ei    = (const int*)d_in[1];
    const int*   et    = (const int*)d_in[2];
    const int*   batch = (const int*)d_in[3];
    const float* W0    = (const float*)d_in[4];
    const float* root0 = (const float*)d_in[5];
    const float* b0    = (const float*)d_in[6];
    const float* ln0g  = (const float*)d_in[7];
    const float* ln0b  = (const float*)d_in[8];
    const float* resw  = (const float*)d_in[9];
    const float* resb  = (const float*)d_in[10];
    const float* W1    = (const float*)d_in[11];
    const float* root1 = (const float*)d_in[12];
    const float* b1    = (const float*)d_in[13];
    const float* ln1g  = (const float*)d_in[14];
    const float* ln1b  = (const float*)d_in[15];
    const float* W2    = (const float*)d_in[16];
    const float* root2 = (const float*)d_in[17];
    const float* b2    = (const float*)d_in[18];
    const float* ln2g  = (const float*)d_in[19];
    const float* ln2b  = (const float*)d_in[20];
    const float* row1  = (const float*)d_in[21];
    const float* rob1  = (const float*)d_in[22];
    const float* row2  = (const float*)d_in[23];
    const float* rob2  = (const float*)d_in[24];
    float* out = (float*)d_out;

    char* ws = (char*)d_ws;
    size_t off = 0;
    int* cnt = (int*)(ws + off);    off += (size_t)NNODES * NREL * 4;      // 1.6 MB
    int* gcnt = (int*)(ws + off);   off += 4096;
    float* pooled = (float*)(ws + off); off += (size_t)NGRAPH * HID * 4;   // 256 KB
    size_t sums_bytes = (size_t)NNODES * NREL * HID * 4;                   // 102.4 MB
    float* sums = (float*)(ws + off);
    size_t zero_bytes = off + sums_bytes;   // cnt..sums contiguous
    off += sums_bytes;
    float* xA = (float*)(ws + off); off += (size_t)NNODES * HID * 4;       // 25.6 MB
    float* xB = (float*)(ws + off); off += (size_t)NNODES * HID * 4;

    // zero cnt, gcnt, pooled, sums in one memset
    hipMemsetAsync(d_ws, 0, zero_bytes, stream);

    count_kernel<<<(NEDGES + 255) / 256, 256, 0, stream>>>(ei, et, batch, cnt, gcnt);

    // ---- layer 0 ----
    scatter_kernel<DIN><<<NEDGES / 256, 256, 0, stream>>>(x, ei, et, sums);
    transform0_kernel<<<(NNODES + TN - 1) / TN, 256, 0, stream>>>(
        x, sums, cnt, W0, root0, b0, ln0g, ln0b, resw, resb, xA);

    // ---- layer 1 ----
    hipMemsetAsync(sums, 0, sums_bytes, stream);
    scatter_kernel<HID><<<NEDGES / 256, 256, 0, stream>>>(xA, ei, et, sums);
    transform12_kernel<false><<<(NNODES + TN - 1) / TN, 256, 0, stream>>>(
        xA, sums, cnt, W1, root1, b1, ln1g, ln1b, batch, xB);

    // ---- layer 2 (pool fused) ----
    hipMemsetAsync(sums, 0, sums_bytes, stream);
    scatter_kernel<HID><<<NEDGES / 256, 256, 0, stream>>>(xB, ei, et, sums);
    transform12_kernel<true><<<(NNODES + TN - 1) / TN, 256, 0, stream>>>(
        xB, sums, cnt, W2, root2, b2, ln2g, ln2b, batch, pooled);

    // ---- readout ----
    readout_kernel<<<(NGRAPH + 3) / 4, 256, 0, stream>>>(
        pooled, gcnt, row1, rob1, row2, rob2, out);
}

// Round 2
// 1070.867 us; speedup vs baseline: 2.6348x; 2.6348x over previous
//
#include <hip/hip_runtime.h>
#include <math.h>

#define NNODES 100000
#define NEDGES 1600000
#define NREL   4
#define DIN    38
#define HID    64
#define NGRAPH 1000
#define NSEG   (NNODES * NREL)          // 400000
#define NSCANB ((NSEG + 1023) / 1024)   // 391
#define LSTR   68                       // LDS row stride (floats): 16B-aligned float4, bank-spread

// ---------------------------------------------------------------------------
// counts: cnt[node*R+rel] edge counts, gcnt[g] nodes per graph
// ---------------------------------------------------------------------------
__global__ __launch_bounds__(256) void count_kernel(
    const int* __restrict__ ei, const int* __restrict__ et,
    const int* __restrict__ batch, int* __restrict__ cnt,
    int* __restrict__ gcnt) {
    int i = blockIdx.x * 256 + threadIdx.x;
    if (i < NEDGES) {
        int dst = ei[NEDGES + i];
        atomicAdd(&cnt[dst * NREL + et[i]], 1);
    }
    if (i < NNODES) {
        atomicAdd(&gcnt[batch[i]], 1);
    }
}

// ---------------------------------------------------------------------------
// scan1: per-1024-chunk exclusive scan of cnt -> excl, chunk totals -> bsum
// ---------------------------------------------------------------------------
__global__ __launch_bounds__(256) void scan1_kernel(
    const int* __restrict__ cnt, int* __restrict__ excl, int* __restrict__ bsum) {
    __shared__ int tmp[256];
    int tid = threadIdx.x;
    int base = blockIdx.x * 1024 + tid * 4;
    int v0 = 0, v1 = 0, v2 = 0, v3 = 0;
    if (base + 0 < NSEG) v0 = cnt[base + 0];
    if (base + 1 < NSEG) v1 = cnt[base + 1];
    if (base + 2 < NSEG) v2 = cnt[base + 2];
    if (base + 3 < NSEG) v3 = cnt[base + 3];
    int s = v0 + v1 + v2 + v3;
    tmp[tid] = s;
    __syncthreads();
    for (int off = 1; off < 256; off <<= 1) {
        int t = (tid >= off) ? tmp[tid - off] : 0;
        __syncthreads();
        tmp[tid] += t;
        __syncthreads();
    }
    if (tid == 255) bsum[blockIdx.x] = tmp[255];
    int run = tmp[tid] - s;
    if (base + 0 < NSEG) excl[base + 0] = run; run += v0;
    if (base + 1 < NSEG) excl[base + 1] = run; run += v1;
    if (base + 2 < NSEG) excl[base + 2] = run; run += v2;
    if (base + 3 < NSEG) excl[base + 3] = run;
}

// scan2: exclusive scan of bsum[NSCANB] in one block
__global__ __launch_bounds__(512) void scan2_kernel(int* __restrict__ bsum) {
    __shared__ int tmp[512];
    int tid = threadIdx.x;
    int v = (tid < NSCANB) ? bsum[tid] : 0;
    tmp[tid] = v;
    __syncthreads();
    for (int off = 1; off < 512; off <<= 1) {
        int t = (tid >= off) ? tmp[tid - off] : 0;
        __syncthreads();
        tmp[tid] += t;
        __syncthreads();
    }
    if (tid < NSCANB) bsum[tid] = tmp[tid] - v;
}

// ---------------------------------------------------------------------------
// place: CSR bucket fill. esrc[excl[seg]+bsum[seg>>10] + k] = src of k-th edge
// ---------------------------------------------------------------------------
__global__ __launch_bounds__(256) void place_kernel(
    const int* __restrict__ ei, const int* __restrict__ et,
    const int* __restrict__ excl, const int* __restrict__ bsum,
    int* __restrict__ fill, int* __restrict__ esrc) {
    int e = blockIdx.x * 256 + threadIdx.x;
    if (e >= NEDGES) return;
    int seg = ei[NEDGES + e] * NREL + et[e];
    int pos = excl[seg] + bsum[seg >> 10] + atomicAdd(&fill[seg], 1);
    esrc[pos] = ei[e];
}

// ---------------------------------------------------------------------------
// aggregate: one wave per segment; lane = channel. mean[seg*F+f] coalesced.
// ---------------------------------------------------------------------------
template <int F>
__global__ __launch_bounds__(256) void aggregate_kernel(
    const float* __restrict__ x, const int* __restrict__ esrc,
    const int* __restrict__ excl, const int* __restrict__ bsum,
    const int* __restrict__ cnt, float* __restrict__ mean) {
    int wid = (blockIdx.x * 256 + threadIdx.x) >> 6;
    int lane = threadIdx.x & 63;
    if (wid >= NSEG) return;
    int beg = excl[wid] + bsum[wid >> 10];
    int c = cnt[wid];
    float acc = 0.f;
    for (int base = 0; base < c; base += 64) {
        int ce = c - base; if (ce > 64) ce = 64;
        int my = (lane < ce) ? esrc[beg + base + lane] : 0;
        for (int i = 0; i < ce; ++i) {
            int s = __shfl(my, i);
            if (lane < F) acc += x[(size_t)s * F + lane];
        }
    }
    if (lane < F) {
        float cc = c > 0 ? (float)c : 1.f;
        mean[(size_t)wid * F + lane] = acc * (1.f / cc);
    }
}

__device__ __forceinline__ void ln_group_reduce(float& s) {
    s += __shfl_xor(s, 1);
    s += __shfl_xor(s, 2);
    s += __shfl_xor(s, 4);
    s += __shfl_xor(s, 8);
}

// ---------------------------------------------------------------------------
// transform layers 1/2: tiled GEMM. M-tile=64 nodes, N=64, K=320
// A_virtual[n][k] = k<256 ? mean[n*256+k] : xprev[n*64+k-256]
// out = LN(relu(acc + bias) + xprev). POOL: atomic accumulate into pooled.
// ---------------------------------------------------------------------------
template <bool POOL>
__global__ __launch_bounds__(256, 4) void transform12_kernel(
    const float* __restrict__ xprev, const float* __restrict__ mean,
    const float* __restrict__ W, const float* __restrict__ root,
    const float* __restrict__ bias, const float* __restrict__ lng,
    const float* __restrict__ lnb, const int* __restrict__ batch,
    float* __restrict__ dst) {
    __shared__ float As[32][LSTR];
    __shared__ float Ws[32][LSTR];
    int tid = threadIdx.x;
    int nbase = blockIdx.x * 64;
    int r = tid >> 4, c = tid & 15;
    float acc[4][4] = {};

    int sk = tid & 31;        // staging k
    int sm0 = tid >> 5;       // staging m start (0..7)
    int scc = tid & 63;       // weight staging col
    int sk0 = tid >> 6;       // weight staging k start (0..3)

    for (int ch = 0; ch < 10; ++ch) {
        int kbeg = ch * 32;
        #pragma unroll
        for (int mm = 0; mm < 8; ++mm) {
            int m = sm0 + mm * 8;
            int n = nbase + m; if (n > NNODES - 1) n = NNODES - 1;
            int t = kbeg + sk;
            As[sk][m] = (t < 256) ? mean[(size_t)n * 256 + t]
                                  : xprev[(size_t)n * 64 + (t - 256)];
        }
        #pragma unroll
        for (int kk = 0; kk < 8; ++kk) {
            int k = sk0 + kk * 4;
            int t = kbeg + k;
            Ws[k][scc] = (t < 256) ? W[t * 64 + scc] : root[(t - 256) * 64 + scc];
        }
        __syncthreads();
        #pragma unroll 4
        for (int k = 0; k < 32; ++k) {
            const float4 av = *(const float4*)(&As[k][r * 4]);
            const float4 wv = *(const float4*)(&Ws[k][c * 4]);
            const float a_[4] = {av.x, av.y, av.z, av.w};
            const float w_[4] = {wv.x, wv.y, wv.z, wv.w};
            #pragma unroll
            for (int i = 0; i < 4; ++i)
                #pragma unroll
                for (int j = 0; j < 4; ++j)
                    acc[i][j] += a_[i] * w_[j];
        }
        __syncthreads();
    }

    // epilogue: relu + residual + LayerNorm over 64 cols (16-lane c-group)
    const float4 bv = *(const float4*)&bias[c * 4];
    const float4 gv = *(const float4*)&lng[c * 4];
    const float4 be = *(const float4*)&lnb[c * 4];
    const float b_[4] = {bv.x, bv.y, bv.z, bv.w};
    const float g_[4] = {gv.x, gv.y, gv.z, gv.w};
    const float e_[4] = {be.x, be.y, be.z, be.w};
    #pragma unroll
    for (int i = 0; i < 4; ++i) {
        int n = nbase + r * 4 + i;
        int nc = n > NNODES - 1 ? NNODES - 1 : n;
        const float4 rv = *(const float4*)&xprev[(size_t)nc * 64 + c * 4];
        const float r_[4] = {rv.x, rv.y, rv.z, rv.w};
        float u[4];
        float s = 0.f;
        #pragma unroll
        for (int j = 0; j < 4; ++j) { u[j] = fmaxf(acc[i][j] + b_[j], 0.f) + r_[j]; s += u[j]; }
        ln_group_reduce(s);
        float mu = s * (1.f / 64.f);
        float q = 0.f;
        #pragma unroll
        for (int j = 0; j < 4; ++j) { u[j] -= mu; q += u[j] * u[j]; }
        ln_group_reduce(q);
        float inv = 1.f / sqrtf(q * (1.f / 64.f) + 1e-5f);
        float o[4];
        #pragma unroll
        for (int j = 0; j < 4; ++j) o[j] = u[j] * inv * g_[j] + e_[j];
        if (n < NNODES) {
            if (POOL) {
                int g = batch[n];
                #pragma unroll
                for (int j = 0; j < 4; ++j)
                    atomicAdd(dst + (size_t)g * 64 + c * 4 + j, o[j]);
            } else {
                *(float4*)&dst[(size_t)n * 64 + c * 4] = make_float4(o[0], o[1], o[2], o[3]);
            }
        }
    }
}

// ---------------------------------------------------------------------------
// transform layer 0: accA over K=190 (W0|root0, zero-padded to 192),
// accB over K=38 (res_w, zero-padded to 64).
// x1 = LN(relu(accA + b0) + accB + res_b)
// ---------------------------------------------------------------------------
__global__ __launch_bounds__(256, 4) void transform0_kernel(
    const float* __restrict__ x, const float* __restrict__ mean0,
    const float* __restrict__ W0, const float* __restrict__ root0,
    const float* __restrict__ b0, const float* __restrict__ lng,
    const float* __restrict__ lnb, const float* __restrict__ resw,
    const float* __restrict__ resb, float* __restrict__ x1) {
    __shared__ float As[32][LSTR];
    __shared__ float Ws[32][LSTR];
    int tid = threadIdx.x;
    int nbase = blockIdx.x * 64;
    int r = tid >> 4, c = tid & 15;
    float accA[4][4] = {};
    float accB[4][4] = {};

    int sk = tid & 31;
    int sm0 = tid >> 5;
    int scc = tid & 63;
    int sk0 = tid >> 6;

    // part A: 6 chunks covering t in [0,190) (W0 rows then root0 rows)
    for (int ch = 0; ch < 6; ++ch) {
        int kbeg = ch * 32;
        #pragma unroll
        for (int mm = 0; mm < 8; ++mm) {
            int m = sm0 + mm * 8;
            int n = nbase + m; if (n > NNODES - 1) n = NNODES - 1;
            int t = kbeg + sk;
            float v = 0.f;
            if (t < 152)      v = mean0[(size_t)n * 152 + t];
            else if (t < 190) v = x[(size_t)n * DIN + (t - 152)];
            As[sk][m] = v;
        }
        #pragma unroll
        for (int kk = 0; kk < 8; ++kk) {
            int k = sk0 + kk * 4;
            int t = kbeg + k;
            float w = 0.f;
            if (t < 152)      w = W0[t * 64 + scc];
            else if (t < 190) w = root0[(t - 152) * 64 + scc];
            Ws[k][scc] = w;
        }
        __syncthreads();
        #pragma unroll 4
        for (int k = 0; k < 32; ++k) {
            const float4 av = *(const float4*)(&As[k][r * 4]);
            const float4 wv = *(const float4*)(&Ws[k][c * 4]);
            const float a_[4] = {av.x, av.y, av.z, av.w};
            const float w_[4] = {wv.x, wv.y, wv.z, wv.w};
            #pragma unroll
            for (int i = 0; i < 4; ++i)
                #pragma unroll
                for (int j = 0; j < 4; ++j)
                    accA[i][j] += a_[i] * w_[j];
        }
        __syncthreads();
    }
    // part B: 2 chunks covering t' in [0,38) (res_w rows)
    for (int ch = 0; ch < 2; ++ch) {
        int kbeg = ch * 32;
        #pragma unroll
        for (int mm = 0; mm < 8; ++mm) {
            int m = sm0 + mm * 8;
            int n = nbase + m; if (n > NNODES - 1) n = NNODES - 1;
            int t = kbeg + sk;
            As[sk][m] = (t < DIN) ? x[(size_t)n * DIN + t] : 0.f;
        }
        #pragma unroll
        for (int kk = 0; kk < 8; ++kk) {
            int k = sk0 + kk * 4;
            int t = kbeg + k;
            Ws[k][scc] = (t < DIN) ? resw[t * 64 + scc] : 0.f;
        }
        __syncthreads();
        #pragma unroll 4
        for (int k = 0; k < 32; ++k) {
            const float4 av = *(const float4*)(&As[k][r * 4]);
            const float4 wv = *(const float4*)(&Ws[k][c * 4]);
            const float a_[4] = {av.x, av.y, av.z, av.w};
            const float w_[4] = {wv.x, wv.y, wv.z, wv.w};
            #pragma unroll
            for (int i = 0; i < 4; ++i)
                #pragma unroll
                for (int j = 0; j < 4; ++j)
                    accB[i][j] += a_[i] * w_[j];
        }
        __syncthreads();
    }

    const float4 bv = *(const float4*)&b0[c * 4];
    const float4 sv = *(const float4*)&resb[c * 4];
    const float4 gv = *(const float4*)&lng[c * 4];
    const float4 be = *(const float4*)&lnb[c * 4];
    const float b_[4] = {bv.x, bv.y, bv.z, bv.w};
    const float s_[4] = {sv.x, sv.y, sv.z, sv.w};
    const float g_[4] = {gv.x, gv.y, gv.z, gv.w};
    const float e_[4] = {be.x, be.y, be.z, be.w};
    #pragma unroll
    for (int i = 0; i < 4; ++i) {
        int n = nbase + r * 4 + i;
        float u[4];
        float s = 0.f;
        #pragma unroll
        for (int j = 0; j < 4; ++j) {
            u[j] = fmaxf(accA[i][j] + b_[j], 0.f) + accB[i][j] + s_[j];
            s += u[j];
        }
        ln_group_reduce(s);
        float mu = s * (1.f / 64.f);
        float q = 0.f;
        #pragma unroll
        for (int j = 0; j < 4; ++j) { u[j] -= mu; q += u[j] * u[j]; }
        ln_group_reduce(q);
        float inv = 1.f / sqrtf(q * (1.f / 64.f) + 1e-5f);
        if (n < NNODES) {
            float o[4];
            #pragma unroll
            for (int j = 0; j < 4; ++j) o[j] = u[j] * inv * g_[j] + e_[j];
            *(float4*)&x1[(size_t)n * 64 + c * 4] = make_float4(o[0], o[1], o[2], o[3]);
        }
    }
}

// ---------------------------------------------------------------------------
// readout: out[g] = relu(pooled[g]/cnt @ ro_w1 + ro_b1) @ ro_w2 + ro_b2
// ---------------------------------------------------------------------------
__global__ __launch_bounds__(256) void readout_kernel(
    const float* __restrict__ pooled, const int* __restrict__ gcnt,
    const float* __restrict__ w1, const float* __restrict__ b1,
    const float* __restrict__ w2, const float* __restrict__ b2,
    float* __restrict__ out) {
    __shared__ float wl[64][64];
    int tid = threadIdx.x;
    for (int idx = tid; idx < 64 * 64; idx += 256) {
        wl[idx >> 6][idx & 63] = w1[idx];
    }
    __syncthreads();
    int wv = tid >> 6, lane = tid & 63;
    int g = blockIdx.x * 4 + wv;
    if (g >= NGRAPH) return;
    int cc = gcnt[g];
    float cf = cc > 0 ? (float)cc : 1.0f;
    float p = pooled[(size_t)g * 64 + lane] / cf;
    float acc = b1[lane];
    for (int f = 0; f < 64; ++f) {
        acc += __shfl(p, f) * wl[f][lane];
    }
    float t = fmaxf(acc, 0.f);
    float v = t * w2[lane];
    #pragma unroll
    for (int o = 32; o; o >>= 1) v += __shfl_xor(v, o);
    if (lane == 0) out[g] = v + b2[0];
}

// ---------------------------------------------------------------------------
extern "C" void kernel_launch(void* const* d_in, const int* in_sizes, int n_in,
                              void* d_out, int out_size, void* d_ws, size_t ws_size,
                              hipStream_t stream) {
    const float* x     = (const float*)d_in[0];
    const int*   ei    = (const int*)d_in[1];
    const int*   et    = (const int*)d_in[2];
    const int*   batch = (const int*)d_in[3];
    const float* W0    = (const float*)d_in[4];
    const float* root0 = (const float*)d_in[5];
    const float* b0    = (const float*)d_in[6];
    const float* ln0g  = (const float*)d_in[7];
    const float* ln0b  = (const float*)d_in[8];
    const float* resw  = (const float*)d_in[9];
    const float* resb  = (const float*)d_in[10];
    const float* W1    = (const float*)d_in[11];
    const float* root1 = (const float*)d_in[12];
    const float* b1    = (const float*)d_in[13];
    const float* ln1g  = (const float*)d_in[14];
    const float* ln1b  = (const float*)d_in[15];
    const float* W2    = (const float*)d_in[16];
    const float* root2 = (const float*)d_in[17];
    const float* b2    = (const float*)d_in[18];
    const float* ln2g  = (const float*)d_in[19];
    const float* ln2b  = (const float*)d_in[20];
    const float* row1  = (const float*)d_in[21];
    const float* rob1  = (const float*)d_in[22];
    const float* row2  = (const float*)d_in[23];
    const float* rob2  = (const float*)d_in[24];
    float* out = (float*)d_out;

    char* ws = (char*)d_ws;
    size_t off = 0;
    int* cnt    = (int*)(ws + off); off += (size_t)NSEG * 4;        // 1.6 MB
    int* fill   = (int*)(ws + off); off += (size_t)NSEG * 4;        // 1.6 MB
    int* gcnt   = (int*)(ws + off); off += 4096;
    float* pooled = (float*)(ws + off); off += (size_t)NGRAPH * 64 * 4;
    size_t zero_bytes = off;                                        // ~3.46 MB
    int* excl   = (int*)(ws + off); off += (size_t)NSEG * 4;
    int* bsum   = (int*)(ws + off); off += 4096;
    int* esrc   = (int*)(ws + off); off += (size_t)NEDGES * 4;      // 6.4 MB
    float* mean = (float*)(ws + off); off += (size_t)NSEG * HID * 4; // 102.4 MB
    float* xA   = (float*)(ws + off); off += (size_t)NNODES * HID * 4;
    float* xB   = (float*)(ws + off); off += (size_t)NNODES * HID * 4;

    hipMemsetAsync(d_ws, 0, zero_bytes, stream);

    count_kernel<<<6250, 256, 0, stream>>>(ei, et, batch, cnt, gcnt);
    scan1_kernel<<<NSCANB, 256, 0, stream>>>(cnt, excl, bsum);
    scan2_kernel<<<1, 512, 0, stream>>>(bsum);
    place_kernel<<<6250, 256, 0, stream>>>(ei, et, excl, bsum, fill, esrc);

    const int TBLK = (NNODES + 63) / 64;   // 1563
    const int ABLK = NSEG / 4;             // 100000 blocks (4 waves each)

    // ---- layer 0 ----
    aggregate_kernel<DIN><<<ABLK, 256, 0, stream>>>(x, esrc, excl, bsum, cnt, mean);
    transform0_kernel<<<TBLK, 256, 0, stream>>>(
        x, mean, W0, root0, b0, ln0g, ln0b, resw, resb, xA);

    // ---- layer 1 ----
    aggregate_kernel<HID><<<ABLK, 256, 0, stream>>>(xA, esrc, excl, bsum, cnt, mean);
    transform12_kernel<false><<<TBLK, 256, 0, stream>>>(
        xA, mean, W1, root1, b1, ln1g, ln1b, batch, xB);

    // ---- layer 2 (pool fused) ----
    aggregate_kernel<HID><<<ABLK, 256, 0, stream>>>(xB, esrc, excl, bsum, cnt, mean);
    transform12_kernel<true><<<TBLK, 256, 0, stream>>>(
        xB, mean, W2, root2, b2, ln2g, ln2b, batch, pooled);

    // ---- readout ----
    readout_kernel<<<250, 256, 0, stream>>>(
        pooled, gcnt, row1, rob1, row2, rob2, out);
}

// Round 4
// 884.486 us; speedup vs baseline: 3.1901x; 1.2107x over previous
//
#include <hip/hip_runtime.h>
#include <math.h>

#define NNODES 100000
#define NEDGES 1600000
#define NREL   4
#define DIN    38
#define HID    64
#define NGRAPH 1000
#define NSEG   (NNODES * NREL)          // 400000
#define NSCANB ((NSEG + 1023) / 1024)   // 391
#define YW     320                      // y row width (4 rel slices + root slice)

__device__ __forceinline__ float wsum64(float v) {
    #pragma unroll
    for (int o = 32; o; o >>= 1) v += __shfl_xor(v, o);
    return v;
}

// ---------------------------------------------------------------------------
// counts: cnt[node*R+rel] edge counts, gcnt[g] nodes per graph
// ---------------------------------------------------------------------------
__global__ __launch_bounds__(256) void count_kernel(
    const int* __restrict__ ei, const int* __restrict__ et,
    const int* __restrict__ batch, int* __restrict__ cnt,
    int* __restrict__ gcnt) {
    int i = blockIdx.x * 256 + threadIdx.x;
    if (i < NEDGES) {
        int dst = ei[NEDGES + i];
        atomicAdd(&cnt[dst * NREL + et[i]], 1);
    }
    if (i < NNODES) {
        atomicAdd(&gcnt[batch[i]], 1);
    }
}

// ---------------------------------------------------------------------------
// scan1: per-1024-chunk exclusive scan of cnt -> excl, chunk totals -> bsum
// ---------------------------------------------------------------------------
__global__ __launch_bounds__(256) void scan1_kernel(
    const int* __restrict__ cnt, int* __restrict__ excl, int* __restrict__ bsum) {
    __shared__ int tmp[256];
    int tid = threadIdx.x;
    int base = blockIdx.x * 1024 + tid * 4;
    int v0 = 0, v1 = 0, v2 = 0, v3 = 0;
    if (base + 0 < NSEG) v0 = cnt[base + 0];
    if (base + 1 < NSEG) v1 = cnt[base + 1];
    if (base + 2 < NSEG) v2 = cnt[base + 2];
    if (base + 3 < NSEG) v3 = cnt[base + 3];
    int s = v0 + v1 + v2 + v3;
    tmp[tid] = s;
    __syncthreads();
    for (int off = 1; off < 256; off <<= 1) {
        int t = (tid >= off) ? tmp[tid - off] : 0;
        __syncthreads();
        tmp[tid] += t;
        __syncthreads();
    }
    if (tid == 255) bsum[blockIdx.x] = tmp[255];
    int run = tmp[tid] - s;
    if (base + 0 < NSEG) excl[base + 0] = run; run += v0;
    if (base + 1 < NSEG) excl[base + 1] = run; run += v1;
    if (base + 2 < NSEG) excl[base + 2] = run; run += v2;
    if (base + 3 < NSEG) excl[base + 3] = run;
}

// scan2: exclusive scan of bsum[NSCANB] in one block
__global__ __launch_bounds__(512) void scan2_kernel(int* __restrict__ bsum) {
    __shared__ int tmp[512];
    int tid = threadIdx.x;
    int v = (tid < NSCANB) ? bsum[tid] : 0;
    tmp[tid] = v;
    __syncthreads();
    for (int off = 1; off < 512; off <<= 1) {
        int t = (tid >= off) ? tmp[tid - off] : 0;
        __syncthreads();
        tmp[tid] += t;
        __syncthreads();
    }
    if (tid < NSCANB) bsum[tid] = tmp[tid] - v;
}

// ---------------------------------------------------------------------------
// place: CSR bucket fill. packed entry = src | (rel << 20)
// ---------------------------------------------------------------------------
__global__ __launch_bounds__(256) void place_kernel(
    const int* __restrict__ ei, const int* __restrict__ et,
    const int* __restrict__ excl, const int* __restrict__ bsum,
    int* __restrict__ fill, int* __restrict__ esrc) {
    int e = blockIdx.x * 256 + threadIdx.x;
    if (e >= NEDGES) return;
    int r = et[e];
    int seg = ei[NEDGES + e] * NREL + r;
    int pos = excl[seg] + bsum[seg >> 10] + atomicAdd(&fill[seg], 1);
    esrc[pos] = ei[e] | (r << 20);
}

// ---------------------------------------------------------------------------
// gemm12: y[n][nc*64+ch] = sum_k x[n][k] * B[k][gc],  B = [W_r0..W_r3 | root]
// x: [N,64], W: [4*64,64] (r*4096 + k*64 + ch), root: [64,64], y: [N,320]
// ---------------------------------------------------------------------------
__global__ __launch_bounds__(256, 4) void gemm12_kernel(
    const float* __restrict__ x, const float* __restrict__ W,
    const float* __restrict__ root, float* __restrict__ y) {
    __shared__ float As[64][68];
    __shared__ float Ws[64][68];
    int tid = threadIdx.x;
    int nbase = blockIdx.x * 64;

    {   // stage As (full K=64)
        int sk = tid & 63, sm0 = tid >> 6;
        #pragma unroll
        for (int mm = 0; mm < 16; ++mm) {
            int m = sm0 + mm * 4;
            int n = nbase + m; if (n > NNODES - 1) n = NNODES - 1;
            As[sk][m] = x[(size_t)n * 64 + sk];
        }
    }
    int r = tid >> 4, c = tid & 15;
    int scc = tid & 63, sk0 = tid >> 6;

    for (int nc = 0; nc < 5; ++nc) {
        __syncthreads();
        const float* src = (nc < 4) ? (W + nc * 4096) : root;
        #pragma unroll
        for (int kk = 0; kk < 16; ++kk) {
            int k = sk0 + kk * 4;
            Ws[k][scc] = src[k * 64 + scc];
        }
        __syncthreads();
        float acc[4][4] = {};
        #pragma unroll 4
        for (int k = 0; k < 64; ++k) {
            const float4 av = *(const float4*)&As[k][r * 4];
            const float4 wv = *(const float4*)&Ws[k][c * 4];
            const float a_[4] = {av.x, av.y, av.z, av.w};
            const float w_[4] = {wv.x, wv.y, wv.z, wv.w};
            #pragma unroll
            for (int i = 0; i < 4; ++i)
                #pragma unroll
                for (int j = 0; j < 4; ++j)
                    acc[i][j] += a_[i] * w_[j];
        }
        #pragma unroll
        for (int i = 0; i < 4; ++i) {
            int n = nbase + r * 4 + i;
            if (n < NNODES)
                *(float4*)&y[(size_t)n * YW + nc * 64 + c * 4] =
                    make_float4(acc[i][0], acc[i][1], acc[i][2], acc[i][3]);
        }
    }
}

// ---------------------------------------------------------------------------
// gemm0: x [N,38]; chunks 0-3: W0 slices, 4: root0 -> y[N,320];
//        chunk 5: res_w -> xres[N,64]
// ---------------------------------------------------------------------------
__global__ __launch_bounds__(256, 4) void gemm0_kernel(
    const float* __restrict__ x, const float* __restrict__ W0,
    const float* __restrict__ root0, const float* __restrict__ resw,
    float* __restrict__ y, float* __restrict__ xres) {
    __shared__ float As[38][68];
    __shared__ float Ws[38][68];
    int tid = threadIdx.x;
    int nbase = blockIdx.x * 64;

    for (int idx = tid; idx < 64 * 38; idx += 256) {
        int m = idx / 38, k = idx - m * 38;
        int n = nbase + m; if (n > NNODES - 1) n = NNODES - 1;
        As[k][m] = x[(size_t)n * DIN + k];
    }
    int r = tid >> 4, c = tid & 15;

    for (int nc = 0; nc < 6; ++nc) {
        __syncthreads();
        const float* src = (nc < 4) ? (W0 + nc * DIN * 64)
                                    : (nc == 4 ? root0 : resw);
        for (int idx = tid; idx < 38 * 64; idx += 256) {
            int k = idx >> 6, cc = idx & 63;
            Ws[k][cc] = src[idx];
        }
        __syncthreads();
        float acc[4][4] = {};
        #pragma unroll 2
        for (int k = 0; k < 38; ++k) {
            const float4 av = *(const float4*)&As[k][r * 4];
            const float4 wv = *(const float4*)&Ws[k][c * 4];
            const float a_[4] = {av.x, av.y, av.z, av.w};
            const float w_[4] = {wv.x, wv.y, wv.z, wv.w};
            #pragma unroll
            for (int i = 0; i < 4; ++i)
                #pragma unroll
                for (int j = 0; j < 4; ++j)
                    acc[i][j] += a_[i] * w_[j];
        }
        #pragma unroll
        for (int i = 0; i < 4; ++i) {
            int n = nbase + r * 4 + i;
            if (n < NNODES) {
                float4 o = make_float4(acc[i][0], acc[i][1], acc[i][2], acc[i][3]);
                if (nc < 5) *(float4*)&y[(size_t)n * YW + nc * 64 + c * 4] = o;
                else        *(float4*)&xres[(size_t)n * 64 + c * 4] = o;
            }
        }
    }
}

// ---------------------------------------------------------------------------
// epilogue: one wave per node. Gather per-edge y[src][r*64+ch], per-relation
// mean, + root slice + bias, ReLU, + residual (+resb if L0), LayerNorm.
// POOL: atomic accumulate into pooled[batch[n]].
// ---------------------------------------------------------------------------
template <bool L0, bool POOL>
__global__ __launch_bounds__(256) void epi_kernel(
    const float* __restrict__ y, const float* __restrict__ xprev,
    const int* __restrict__ esrc, const int* __restrict__ excl,
    const int* __restrict__ bsum, const int* __restrict__ cnt,
    const float* __restrict__ bias, const float* __restrict__ bias2,
    const float* __restrict__ lng, const float* __restrict__ lnb,
    const int* __restrict__ batch, float* __restrict__ dst) {
    int n = (blockIdx.x * 256 + threadIdx.x) >> 6;
    int lane = threadIdx.x & 63;
    if (n >= NNODES) return;

    int s4 = n * 4;
    int myc = 0, myb = 0;
    if (lane < 4) {
        myc = cnt[s4 + lane];
        myb = excl[s4 + lane] + bsum[(s4 + lane) >> 10];
    }
    int c0 = __shfl(myc, 0), c1 = __shfl(myc, 1);
    int c2 = __shfl(myc, 2), c3 = __shfl(myc, 3);
    int beg = __shfl(myb, 0);
    int ctot = c0 + c1 + c2 + c3;

    float a0 = 0.f, a1 = 0.f, a2 = 0.f, a3 = 0.f;
    for (int base = 0; base < ctot; base += 64) {
        int rem = ctot - base; if (rem > 64) rem = 64;
        int ev = (lane < rem) ? esrc[beg + base + lane] : 0;
        for (int i = 0; i < rem; ++i) {
            int raw = __shfl(ev, i);
            int src = raw & 0xFFFFF;
            int rr = raw >> 20;
            float v = y[(size_t)src * YW + (rr << 6) + lane];
            if (rr == 0)      a0 += v;
            else if (rr == 1) a1 += v;
            else if (rr == 2) a2 += v;
            else              a3 += v;
        }
    }
    float agg = a0 / fmaxf((float)c0, 1.f) + a1 / fmaxf((float)c1, 1.f)
              + a2 / fmaxf((float)c2, 1.f) + a3 / fmaxf((float)c3, 1.f);

    float h = fmaxf(agg + y[(size_t)n * YW + 256 + lane] + bias[lane], 0.f);
    float u = h + xprev[(size_t)n * 64 + lane];
    if (L0) u += bias2[lane];

    float mu = wsum64(u) * (1.f / 64.f);
    float d = u - mu;
    float var = wsum64(d * d) * (1.f / 64.f);
    float o = d * (1.f / sqrtf(var + 1e-5f)) * lng[lane] + lnb[lane];

    if (POOL) {
        int g = batch[n];
        atomicAdd(dst + (size_t)g * 64 + lane, o);
    } else {
        dst[(size_t)n * 64 + lane] = o;
    }
}

// ---------------------------------------------------------------------------
// readout: out[g] = relu(pooled[g]/cnt @ ro_w1 + ro_b1) @ ro_w2 + ro_b2
// ---------------------------------------------------------------------------
__global__ __launch_bounds__(256) void readout_kernel(
    const float* __restrict__ pooled, const int* __restrict__ gcnt,
    const float* __restrict__ w1, const float* __restrict__ b1,
    const float* __restrict__ w2, const float* __restrict__ b2,
    float* __restrict__ out) {
    __shared__ float wl[64][64];
    int tid = threadIdx.x;
    for (int idx = tid; idx < 64 * 64; idx += 256) {
        wl[idx >> 6][idx & 63] = w1[idx];
    }
    __syncthreads();
    int wv = tid >> 6, lane = tid & 63;
    int g = blockIdx.x * 4 + wv;
    if (g >= NGRAPH) return;
    int cc = gcnt[g];
    float cf = cc > 0 ? (float)cc : 1.0f;
    float p = pooled[(size_t)g * 64 + lane] / cf;
    float acc = b1[lane];
    for (int f = 0; f < 64; ++f) {
        acc += __shfl(p, f) * wl[f][lane];
    }
    float t = fmaxf(acc, 0.f);
    float v = t * w2[lane];
    v = wsum64(v);
    if (lane == 0) out[g] = v + b2[0];
}

// ---------------------------------------------------------------------------
extern "C" void kernel_launch(void* const* d_in, const int* in_sizes, int n_in,
                              void* d_out, int out_size, void* d_ws, size_t ws_size,
                              hipStream_t stream) {
    const float* x     = (const float*)d_in[0];
    const int*   ei    = (const int*)d_in[1];
    const int*   et    = (const int*)d_in[2];
    const int*   batch = (const int*)d_in[3];
    const float* W0    = (const float*)d_in[4];
    const float* root0 = (const float*)d_in[5];
    const float* b0    = (const float*)d_in[6];
    const float* ln0g  = (const float*)d_in[7];
    const float* ln0b  = (const float*)d_in[8];
    const float* resw  = (const float*)d_in[9];
    const float* resb  = (const float*)d_in[10];
    const float* W1    = (const float*)d_in[11];
    const float* root1 = (const float*)d_in[12];
    const float* b1    = (const float*)d_in[13];
    const float* ln1g  = (const float*)d_in[14];
    const float* ln1b  = (const float*)d_in[15];
    const float* W2    = (const float*)d_in[16];
    const float* root2 = (const float*)d_in[17];
    const float* b2    = (const float*)d_in[18];
    const float* ln2g  = (const float*)d_in[19];
    const float* ln2b  = (const float*)d_in[20];
    const float* row1  = (const float*)d_in[21];
    const float* rob1  = (const float*)d_in[22];
    const float* row2  = (const float*)d_in[23];
    const float* rob2  = (const float*)d_in[24];
    float* out = (float*)d_out;

    char* ws = (char*)d_ws;
    size_t off = 0;
    int* cnt    = (int*)(ws + off); off += (size_t)NSEG * 4;            // 1.6 MB
    int* fill   = (int*)(ws + off); off += (size_t)NSEG * 4;            // 1.6 MB
    int* gcnt   = (int*)(ws + off); off += 4096;
    float* pooled = (float*)(ws + off); off += (size_t)NGRAPH * 64 * 4; // 256 KB
    size_t zero_bytes = off;                                            // ~3.46 MB
    int* excl   = (int*)(ws + off); off += (size_t)NSEG * 4;
    int* bsum   = (int*)(ws + off); off += 4096;
    int* esrc   = (int*)(ws + off); off += (size_t)NEDGES * 4;          // 6.4 MB
    float* y    = (float*)(ws + off); off += (size_t)NNODES * YW * 4;   // 128 MB
    float* xA   = (float*)(ws + off); off += (size_t)NNODES * 64 * 4;   // 25.6 MB
    float* xB   = (float*)(ws + off); off += (size_t)NNODES * 64 * 4;   // 25.6 MB

    hipMemsetAsync(d_ws, 0, zero_bytes, stream);

    count_kernel<<<6250, 256, 0, stream>>>(ei, et, batch, cnt, gcnt);
    scan1_kernel<<<NSCANB, 256, 0, stream>>>(cnt, excl, bsum);
    scan2_kernel<<<1, 512, 0, stream>>>(bsum);
    place_kernel<<<6250, 256, 0, stream>>>(ei, et, excl, bsum, fill, esrc);

    const int GBLK = (NNODES + 63) / 64;   // 1563
    const int EBLK = (NNODES + 3) / 4;     // 25000

    // ---- layer 0 ----
    gemm0_kernel<<<GBLK, 256, 0, stream>>>(x, W0, root0, resw, y, xA);
    epi_kernel<true, false><<<EBLK, 256, 0, stream>>>(
        y, xA, esrc, excl, bsum, cnt, b0, resb, ln0g, ln0b, batch, xA);

    // ---- layer 1 ----
    gemm12_kernel<<<GBLK, 256, 0, stream>>>(xA, W1, root1, y);
    epi_kernel<false, false><<<EBLK, 256, 0, stream>>>(
        y, xA, esrc, excl, bsum, cnt, b1, resb, ln1g, ln1b, batch, xB);

    // ---- layer 2 (pool fused) ----
    gemm12_kernel<<<GBLK, 256, 0, stream>>>(xB, W2, root2, y);
    epi_kernel<false, true><<<EBLK, 256, 0, stream>>>(
        y, xB, esrc, excl, bsum, cnt, b2, resb, ln2g, ln2b, batch, pooled);

    // ---- readout ----
    readout_kernel<<<250, 256, 0, stream>>>(
        pooled, gcnt, row1, rob1, row2, rob2, out);
}